// Round 1
// baseline (4305.932 us; speedup 1.0000x reference)
//
#include <hip/hip_runtime.h>

// LowRankKVCache: out = X @ Vt^T @ Vt where Vt = top-64 eigenvectors of X^T X.
// 64 independent 2048x128 fp32 matrices (B*H = 4*16).
//
// ws layout (bytes):
//   [0, 4M)            G     (64 x 128x128 f32)        -- dead after jacobi_k
//   [4M, 45.81M)       rot   (64 x NSTEPS x 64 float2) -- dead after vapply_k
//   [45.81M, 45.84M)   rank  (64 x 128 int)
//   [45.84M, 47.94M)   Vt    (64 x 64x128 f32)
//   [0, 33.55M)        W     (64 x 2048x64 f32)        -- overlays dead G+rot
// total requirement: ~48 MB of d_ws.

#define NM 64
#define SEQ 2048
#define DD 128
#define RR 64
#define NSWEEP 10
#define NSTEPS (NSWEEP * 127)

#define OFF_ROT  (4194304ULL)
#define OFF_RANK (OFF_ROT + (unsigned long long)NM * NSTEPS * 64 * 8)  // 45,809,664
#define OFF_VT   (OFF_RANK + 32768ULL)                                  // 45,842,432

// round-robin tournament position advance: player at position j moves;
// position 0 fixed, others rotate 1->2->...->127->1.
__device__ __forceinline__ int pstep(int p) {
  return p == 0 ? 0 : (p == 127 ? 1 : p + 1);
}

// ---------------- K1: Gram G[m] = X[m]^T X[m] ----------------
__global__ __launch_bounds__(256) void gram_k(const float* __restrict__ X,
                                              float* __restrict__ G) {
  const int m = blockIdx.y;
  const int r0 = blockIdx.x * 32;  // G row tile (== X column tile)
  const int tid = threadIdx.x;
  __shared__ __align__(16) float Xs[64][128];  // 32 KB
  const float* Xm = X + (size_t)m * SEQ * DD;
  const int ti = tid >> 5;  // 0..7  -> G rows r0+4ti..+3
  const int tj = tid & 31;  // 0..31 -> G cols 4tj..+3
  float acc[4][4];
#pragma unroll
  for (int a = 0; a < 4; ++a)
#pragma unroll
    for (int b = 0; b < 4; ++b) acc[a][b] = 0.f;

  for (int s0 = 0; s0 < SEQ; s0 += 64) {
    __syncthreads();
    for (int t = tid; t < 2048; t += 256) {  // 64 rows x 32 float4
      int s = t >> 5, c4 = t & 31;
      *(float4*)&Xs[s][c4 * 4] =
          *(const float4*)&Xm[(size_t)(s0 + s) * DD + c4 * 4];
    }
    __syncthreads();
#pragma unroll 4
    for (int s = 0; s < 64; ++s) {
      float4 av = *(const float4*)&Xs[s][r0 + 4 * ti];
      float4 bv = *(const float4*)&Xs[s][4 * tj];
      acc[0][0] += av.x * bv.x; acc[0][1] += av.x * bv.y;
      acc[0][2] += av.x * bv.z; acc[0][3] += av.x * bv.w;
      acc[1][0] += av.y * bv.x; acc[1][1] += av.y * bv.y;
      acc[1][2] += av.y * bv.z; acc[1][3] += av.y * bv.w;
      acc[2][0] += av.z * bv.x; acc[2][1] += av.z * bv.y;
      acc[2][2] += av.z * bv.z; acc[2][3] += av.z * bv.w;
      acc[3][0] += av.w * bv.x; acc[3][1] += av.w * bv.y;
      acc[3][2] += av.w * bv.z; acc[3][3] += av.w * bv.w;
    }
  }
  float* Gm = G + (size_t)m * DD * DD;
#pragma unroll
  for (int a = 0; a < 4; ++a) {
    float4 v = make_float4(acc[a][0], acc[a][1], acc[a][2], acc[a][3]);
    *(float4*)&Gm[(size_t)(r0 + 4 * ti + a) * DD + 4 * tj] = v;
  }
}

// ---------------- K2: parallel Jacobi eigensolver on packed symmetric A ----
// One block per matrix. A stored as packed upper triangle (8256 f32, 33 KB).
// Each step: 64 disjoint rotations (round-robin pairing), fused 2x2 update:
// each unordered pair-of-pairs {k,mm} owns a 2x2 block of A exclusively
// (rows pair k x cols pair mm), so in-place update is hazard-free.
// Rotations are streamed to `rot` for replay onto V by vapply_k.
__global__ __launch_bounds__(256) void jacobi_k(const float* __restrict__ G,
                                                float2* __restrict__ rot,
                                                int* __restrict__ rank) {
  const int m = blockIdx.x;
  const int tid = threadIdx.x;
  __shared__ float A[8256];
  __shared__ float cs[64], sn[64];
  __shared__ int rb[128];  // rb[i] = packed row base = i*128 - i(i+1)/2 (excl. j)
  const float* Gm = G + (size_t)m * DD * DD;

  if (tid < 128) rb[tid] = (tid * (255 - tid)) >> 1;
  for (int t = tid; t < DD * DD; t += 256) {
    int i = t >> 7, j = t & 127;
    if (j >= i) A[((i * (255 - i)) >> 1) + j] = Gm[t];
  }

  // Per-thread static item list: items t, t+256, ... over 2080 unordered
  // pair-pairs (k<=mm). Fully unrolled so arrays live in registers.
  int ka[9], ma[9], pk[9], qk[9], pm[9], qm[9];
  bool val[9];
#pragma unroll
  for (int u = 0; u < 9; ++u) {
    int t = tid + 256 * u;
    val[u] = (t < 2080);
    int tt = val[u] ? t : 2079;
    int k = (int)(64.5f - sqrtf(64.5f * 64.5f - 2.0f * (float)tt));
    k = k < 0 ? 0 : (k > 63 ? 63 : k);
    while (k < 63 && (64 * (k + 1) - (((k + 1) * k) >> 1)) <= tt) ++k;
    while (k > 0 && (64 * k - ((k * (k - 1)) >> 1)) > tt) --k;
    int mm = k + (tt - (64 * k - ((k * (k - 1)) >> 1)));
    ka[u] = k; ma[u] = mm;
    // positions at round 0: seq(j,0) = j; pair k = positions (k, 127-k)
    pk[u] = k; qk[u] = 127 - k; pm[u] = mm; qm[u] = 127 - mm;
  }
  int rp = tid, rq = 127 - tid;  // rotation-phase positions (tid<64)
  __syncthreads();

  for (int step = 0; step < NSTEPS; ++step) {
    if (tid < 64) {
      int p = rp, q = rq;
      float app = A[rb[p] + p];
      float aqq = A[rb[q] + q];
      int a_ = p < q ? p : q, b_ = p < q ? q : p;
      float apq = A[rb[a_] + b_];
      float c = 1.f, s = 0.f;
      if (fabsf(apq) > 1e-7f) {
        float tau = (aqq - app) / (2.f * apq);
        float tv = 1.f / (fabsf(tau) + sqrtf(1.f + tau * tau));
        tv = tau < 0.f ? -tv : tv;
        c = 1.f / sqrtf(1.f + tv * tv);
        s = tv * c;
      }
      cs[tid] = c; sn[tid] = s;
      rot[((size_t)m * NSTEPS + step) * 64 + tid] = make_float2(c, s);
    }
    __syncthreads();
#pragma unroll
    for (int u = 0; u < 9; ++u) {
      if (val[u]) {
        int Pk = pk[u], Qk = qk[u], Pm = pm[u], Qm = qm[u];
        float ck = cs[ka[u]], sk = sn[ka[u]];
        float cm = cs[ma[u]], sm = sn[ma[u]];
        int iA, iB;
        iA = Pk < Pm ? Pk : Pm; iB = Pk < Pm ? Pm : Pk; int x00 = rb[iA] + iB;
        iA = Pk < Qm ? Pk : Qm; iB = Pk < Qm ? Qm : Pk; int x01 = rb[iA] + iB;
        iA = Qk < Pm ? Qk : Pm; iB = Qk < Pm ? Pm : Qk; int x10 = rb[iA] + iB;
        iA = Qk < Qm ? Qk : Qm; iB = Qk < Qm ? Qm : Qk; int x11 = rb[iA] + iB;
        float a00 = A[x00], a01 = A[x01], a10 = A[x10], a11 = A[x11];
        // right-multiply by J_mm (column op), then left by J_k^T (row op)
        float b00 = cm * a00 - sm * a01, b01 = sm * a00 + cm * a01;
        float b10 = cm * a10 - sm * a11, b11 = sm * a10 + cm * a11;
        float n00 = ck * b00 - sk * b10, n01 = ck * b01 - sk * b11;
        float n10 = sk * b00 + ck * b10, n11 = sk * b01 + ck * b11;
        if (ka[u] == ma[u]) {
          A[x00] = n00;   // (Pk,Pk) diagonal
          A[x11] = n11;   // (Qk,Qk) diagonal
          A[x01] = 0.f;   // zeroed pivot (x01 == x10 slot)
        } else {
          A[x00] = n00; A[x01] = n01; A[x10] = n10; A[x11] = n11;
        }
      }
    }
    __syncthreads();
    rp = pstep(rp); rq = pstep(rq);
#pragma unroll
    for (int u = 0; u < 9; ++u) {
      pk[u] = pstep(pk[u]); qk[u] = pstep(qk[u]);
      pm[u] = pstep(pm[u]); qm[u] = pstep(qm[u]);
    }
  }

  // rank of each eigenvalue (descending, index tie-break) -> keep rank < 64
  if (tid < 128) {
    float di = A[rb[tid] + tid];
    int cnt = 0;
    for (int j = 0; j < 128; ++j) {
      float dj = A[rb[j] + j];
      cnt += ((dj > di) || (dj == di && j < tid)) ? 1 : 0;
    }
    rank[m * 128 + tid] = cnt;
  }
}

// ---------------- K3: replay rotations onto V = I, emit top-64 rows --------
// Split by 32-row chunks (4 chunks x 64 matrices = 256 blocks). V chunk held
// column-major with stride 44 (16B-aligned float4, banks spread by 44%32=12).
__global__ __launch_bounds__(256) void vapply_k(const float2* __restrict__ rot,
                                                const int* __restrict__ rank,
                                                float* __restrict__ Vt) {
  const int m = blockIdx.y;
  const int r0 = blockIdx.x * 32;
  const int tid = threadIdx.x;
  __shared__ __align__(16) float Vc[128 * 44];  // [col][row_local], 22.5 KB
  __shared__ int rkL[128];

  for (int t = tid; t < 128 * 32; t += 256) {
    int j = t >> 5, i = t & 31;
    Vc[j * 44 + i] = (j == r0 + i) ? 1.f : 0.f;
  }
  if (tid < 128) rkL[tid] = rank[m * 128 + tid];

  const int k0 = tid >> 3;   // pair 0..31
  const int k1 = k0 + 32;    // pair 32..63
  const int g = tid & 7;     // float4 row-group 0..7
  int p0 = k0, q0 = 127 - k0, p1 = k1, q1 = 127 - k1;
  const float2* rm = rot + (size_t)m * NSTEPS * 64;
  float2 c0 = rm[k0], c1 = rm[k1];

  for (int step = 0; step < NSTEPS; ++step) {
    float2 n0 = make_float2(1.f, 0.f), n1 = make_float2(1.f, 0.f);
    if (step + 1 < NSTEPS) {  // prefetch next step's rotations
      n0 = rm[(size_t)(step + 1) * 64 + k0];
      n1 = rm[(size_t)(step + 1) * 64 + k1];
    }
    __syncthreads();
    {
      float4 vp = *(float4*)&Vc[p0 * 44 + 4 * g];
      float4 vq = *(float4*)&Vc[q0 * 44 + 4 * g];
      float4 np, nq;
      np.x = c0.x * vp.x - c0.y * vq.x;  nq.x = c0.y * vp.x + c0.x * vq.x;
      np.y = c0.x * vp.y - c0.y * vq.y;  nq.y = c0.y * vp.y + c0.x * vq.y;
      np.z = c0.x * vp.z - c0.y * vq.z;  nq.z = c0.y * vp.z + c0.x * vq.z;
      np.w = c0.x * vp.w - c0.y * vq.w;  nq.w = c0.y * vp.w + c0.x * vq.w;
      *(float4*)&Vc[p0 * 44 + 4 * g] = np;
      *(float4*)&Vc[q0 * 44 + 4 * g] = nq;
    }
    {
      float4 vp = *(float4*)&Vc[p1 * 44 + 4 * g];
      float4 vq = *(float4*)&Vc[q1 * 44 + 4 * g];
      float4 np, nq;
      np.x = c1.x * vp.x - c1.y * vq.x;  nq.x = c1.y * vp.x + c1.x * vq.x;
      np.y = c1.x * vp.y - c1.y * vq.y;  nq.y = c1.y * vp.y + c1.x * vq.y;
      np.z = c1.x * vp.z - c1.y * vq.z;  nq.z = c1.y * vp.z + c1.x * vq.z;
      np.w = c1.x * vp.w - c1.y * vq.w;  nq.w = c1.y * vp.w + c1.x * vq.w;
      *(float4*)&Vc[p1 * 44 + 4 * g] = np;
      *(float4*)&Vc[q1 * 44 + 4 * g] = nq;
    }
    p0 = pstep(p0); q0 = pstep(q0); p1 = pstep(p1); q1 = pstep(q1);
    c0 = n0; c1 = n1;
  }
  __syncthreads();
  // eigenvector = column j of V; keep if rank<64, as row rk of Vt[m]
  for (int t = tid; t < 128 * 32; t += 256) {
    int j = t >> 5, i = t & 31;
    int rk = rkL[j];
    if (rk < RR) Vt[((size_t)m * RR + rk) * DD + (r0 + i)] = Vc[j * 44 + i];
  }
}

// ---------------- K4: W = X @ Vt^T  (2048x64 per matrix) -------------------
__global__ __launch_bounds__(256) void gemm1_k(const float* __restrict__ X,
                                               const float* __restrict__ Vt,
                                               float* __restrict__ W) {
  const int m = blockIdx.y;
  const int s0 = blockIdx.x * 32;
  const int tid = threadIdx.x;
  __shared__ __align__(16) float VtT[128 * 68];  // [c][r], 34.8 KB
  __shared__ __align__(16) float Xs[32 * 132];   // padded, 16.9 KB
  const float* Vm = Vt + (size_t)m * RR * DD;
  for (int t = tid; t < RR * DD; t += 256) {
    int r = t >> 7, c = t & 127;
    VtT[c * 68 + r] = Vm[t];
  }
  const float* Xm = X + ((size_t)m * SEQ + s0) * DD;
  for (int t = tid; t < 1024; t += 256) {  // 32 rows x 32 float4
    int s = t >> 5, c4 = t & 31;
    *(float4*)&Xs[s * 132 + 4 * c4] = *(const float4*)&Xm[(size_t)s * DD + 4 * c4];
  }
  __syncthreads();
  const int ti = tid >> 4;  // 0..15 -> rows 2ti, 2ti+1
  const int tj = tid & 15;  // cols 4tj..+3
  float acc[2][4] = {{0.f, 0.f, 0.f, 0.f}, {0.f, 0.f, 0.f, 0.f}};
#pragma unroll 4
  for (int k = 0; k < DD; ++k) {
    float a0 = Xs[(2 * ti) * 132 + k];
    float a1 = Xs[(2 * ti + 1) * 132 + k];
    float4 bv = *(float4*)&VtT[k * 68 + 4 * tj];
    acc[0][0] += a0 * bv.x; acc[0][1] += a0 * bv.y;
    acc[0][2] += a0 * bv.z; acc[0][3] += a0 * bv.w;
    acc[1][0] += a1 * bv.x; acc[1][1] += a1 * bv.y;
    acc[1][2] += a1 * bv.z; acc[1][3] += a1 * bv.w;
  }
  float* Wm = W + ((size_t)m * SEQ + s0) * RR;
#pragma unroll
  for (int d = 0; d < 2; ++d) {
    float4 v = make_float4(acc[d][0], acc[d][1], acc[d][2], acc[d][3]);
    *(float4*)&Wm[(size_t)(2 * ti + d) * RR + 4 * tj] = v;
  }
}

// ---------------- K5: out = W @ Vt  (2048x128 per matrix) ------------------
__global__ __launch_bounds__(256) void gemm2_k(const float* __restrict__ W,
                                               const float* __restrict__ Vt,
                                               float* __restrict__ out) {
  const int m = blockIdx.y;
  const int s0 = blockIdx.x * 32;
  const int tid = threadIdx.x;
  __shared__ __align__(16) float Vts[64 * 132];  // 33.8 KB
  __shared__ __align__(16) float Ws[32 * 68];    // 8.7 KB
  const float* Vm = Vt + (size_t)m * RR * DD;
  for (int t = tid; t < 2048; t += 256) {  // 64 rows x 32 float4
    int r = t >> 5, c4 = t & 31;
    *(float4*)&Vts[r * 132 + 4 * c4] = *(const float4*)&Vm[(size_t)r * DD + 4 * c4];
  }
  const float* Wm = W + ((size_t)m * SEQ + s0) * RR;
  for (int t = tid; t < 512; t += 256) {  // 32 rows x 16 float4
    int s = t >> 4, c4 = t & 15;
    *(float4*)&Ws[s * 68 + 4 * c4] = *(const float4*)&Wm[(size_t)s * RR + 4 * c4];
  }
  __syncthreads();
  const int ti = tid >> 5;  // 0..7 -> rows 4ti..+3
  const int tj = tid & 31;  // cols 4tj..+3
  float acc[4][4] = {{0.f,0.f,0.f,0.f},{0.f,0.f,0.f,0.f},
                     {0.f,0.f,0.f,0.f},{0.f,0.f,0.f,0.f}};
#pragma unroll 4
  for (int k = 0; k < RR; ++k) {
    float4 bv = *(float4*)&Vts[k * 132 + 4 * tj];
    float a0 = Ws[(4 * ti + 0) * 68 + k];
    float a1 = Ws[(4 * ti + 1) * 68 + k];
    float a2 = Ws[(4 * ti + 2) * 68 + k];
    float a3 = Ws[(4 * ti + 3) * 68 + k];
    acc[0][0] += a0 * bv.x; acc[0][1] += a0 * bv.y;
    acc[0][2] += a0 * bv.z; acc[0][3] += a0 * bv.w;
    acc[1][0] += a1 * bv.x; acc[1][1] += a1 * bv.y;
    acc[1][2] += a1 * bv.z; acc[1][3] += a1 * bv.w;
    acc[2][0] += a2 * bv.x; acc[2][1] += a2 * bv.y;
    acc[2][2] += a2 * bv.z; acc[2][3] += a2 * bv.w;
    acc[3][0] += a3 * bv.x; acc[3][1] += a3 * bv.y;
    acc[3][2] += a3 * bv.z; acc[3][3] += a3 * bv.w;
  }
  float* Om = out + ((size_t)m * SEQ + s0) * DD;
#pragma unroll
  for (int d = 0; d < 4; ++d) {
    float4 v = make_float4(acc[d][0], acc[d][1], acc[d][2], acc[d][3]);
    *(float4*)&Om[(size_t)(4 * ti + d) * DD + 4 * tj] = v;
  }
}

extern "C" void kernel_launch(void* const* d_in, const int* in_sizes, int n_in,
                              void* d_out, int out_size, void* d_ws, size_t ws_size,
                              hipStream_t stream) {
  (void)in_sizes; (void)n_in; (void)out_size; (void)ws_size;
  const float* X = (const float*)d_in[0];  // rank (d_in[1]) is fixed at 64
  float* out = (float*)d_out;
  char* ws = (char*)d_ws;
  float* G = (float*)ws;
  float2* rot = (float2*)(ws + OFF_ROT);
  int* rank = (int*)(ws + OFF_RANK);
  float* Vt = (float*)(ws + OFF_VT);
  float* W = (float*)ws;  // overlays G+rot, both dead by the time W is written

  gram_k<<<dim3(4, NM), 256, 0, stream>>>(X, G);
  jacobi_k<<<NM, 256, 0, stream>>>(G, rot, rank);
  vapply_k<<<dim3(4, NM), 256, 0, stream>>>(rot, rank, Vt);
  gemm1_k<<<dim3(SEQ / 32, NM), 256, 0, stream>>>(X, Vt, W);
  gemm2_k<<<dim3(SEQ / 32, NM), 256, 0, stream>>>(W, Vt, out);
}

// Round 2
// 2387.321 us; speedup vs baseline: 1.8037x; 1.8037x over previous
//
#include <hip/hip_runtime.h>

// LowRankKVCache: out = X @ Vt^T @ Vt where Vt = top-64 eigenvectors of X^T X.
// 64 independent 2048x128 fp32 matrices (B*H = 4*16).
//
// ws layout (bytes):
//   [0, 4M)              G     (64 x 128x128 f32)        -- dead after jacobi_k
//   [4M, 37.49M)         rot   (64 x NSTEPS x 64 float2) -- dead after vapply_k
//   [37.49M, 37.52M)     rank  (64 x 128 int)
//   [37.52M, 39.62M)     Vt    (64 x 64x128 f32)
//   [0, 33.55M)          W     (64 x 2048x64 f32)        -- overlays dead G+rot
// total requirement: ~40 MB of d_ws.

#define NM 64
#define SEQ 2048
#define DD 128
#define RR 64
#define NSWEEP 8
#define NSTEPS (NSWEEP * 127)

#define OFF_ROT  (4194304ULL)
#define OFF_RANK (OFF_ROT + (unsigned long long)NM * NSTEPS * 64 * 8)
#define OFF_VT   (OFF_RANK + 32768ULL)

// round-robin tournament position advance: player at position j moves;
// position 0 fixed, others rotate 1->2->...->127->1.
__device__ __forceinline__ int pstep(int p) {
  return p == 0 ? 0 : (p == 127 ? 1 : p + 1);
}

// ---------------- K1: Gram G[m] = X[m]^T X[m] ----------------
__global__ __launch_bounds__(256) void gram_k(const float* __restrict__ X,
                                              float* __restrict__ G) {
  const int m = blockIdx.y;
  const int r0 = blockIdx.x * 32;  // G row tile (== X column tile)
  const int tid = threadIdx.x;
  __shared__ __align__(16) float Xs[64][128];  // 32 KB
  const float* Xm = X + (size_t)m * SEQ * DD;
  const int ti = tid >> 5;  // 0..7  -> G rows r0+4ti..+3
  const int tj = tid & 31;  // 0..31 -> G cols 4tj..+3
  float acc[4][4];
#pragma unroll
  for (int a = 0; a < 4; ++a)
#pragma unroll
    for (int b = 0; b < 4; ++b) acc[a][b] = 0.f;

  for (int s0 = 0; s0 < SEQ; s0 += 64) {
    __syncthreads();
    for (int t = tid; t < 2048; t += 256) {  // 64 rows x 32 float4
      int s = t >> 5, c4 = t & 31;
      *(float4*)&Xs[s][c4 * 4] =
          *(const float4*)&Xm[(size_t)(s0 + s) * DD + c4 * 4];
    }
    __syncthreads();
#pragma unroll 4
    for (int s = 0; s < 64; ++s) {
      float4 av = *(const float4*)&Xs[s][r0 + 4 * ti];
      float4 bv = *(const float4*)&Xs[s][4 * tj];
      acc[0][0] += av.x * bv.x; acc[0][1] += av.x * bv.y;
      acc[0][2] += av.x * bv.z; acc[0][3] += av.x * bv.w;
      acc[1][0] += av.y * bv.x; acc[1][1] += av.y * bv.y;
      acc[1][2] += av.y * bv.z; acc[1][3] += av.y * bv.w;
      acc[2][0] += av.z * bv.x; acc[2][1] += av.z * bv.y;
      acc[2][2] += av.z * bv.z; acc[2][3] += av.z * bv.w;
      acc[3][0] += av.w * bv.x; acc[3][1] += av.w * bv.y;
      acc[3][2] += av.w * bv.z; acc[3][3] += av.w * bv.w;
    }
  }
  float* Gm = G + (size_t)m * DD * DD;
#pragma unroll
  for (int a = 0; a < 4; ++a) {
    float4 v = make_float4(acc[a][0], acc[a][1], acc[a][2], acc[a][3]);
    *(float4*)&Gm[(size_t)(r0 + 4 * ti + a) * DD + 4 * tj] = v;
  }
}

// ---------------- K2: parallel Jacobi eigensolver on packed symmetric A ----
// One block (1024 threads, 16 waves) per matrix. A stored as packed upper
// triangle (8256 f32, 33 KB). Each step: 64 disjoint rotations (round-robin
// pairing), fused 2x2 pair-pair update: each unordered pair-of-pairs {k,mm}
// owns a 2x2 block of A exclusively, so in-place update is hazard-free.
// 2080 items / 1024 threads = ~2 per thread (vs 9 at 256 threads): 16 waves
// per CU hide the scattered-b32 LDS latency that capped round 1 at 7% VALU.
__global__ __launch_bounds__(1024) void jacobi_k(const float* __restrict__ G,
                                                 float2* __restrict__ rot,
                                                 int* __restrict__ rank) {
  const int m = blockIdx.x;
  const int tid = threadIdx.x;
  __shared__ float A[8256];
  __shared__ float cs[64], sn[64];
  __shared__ int rb[128];  // rb[i] = packed row base (excl. col index)
  const float* Gm = G + (size_t)m * DD * DD;

  if (tid < 128) rb[tid] = (tid * (255 - tid)) >> 1;
  for (int t = tid; t < DD * DD; t += 1024) {
    int i = t >> 7, j = t & 127;
    if (j >= i) A[((i * (255 - i)) >> 1) + j] = Gm[t];
  }

  // Per-thread static item list over 2080 unordered pair-pairs (k<=mm).
  int ka[3], ma[3], pk[3], qk[3], pm[3], qm[3];
  bool val[3];
#pragma unroll
  for (int u = 0; u < 3; ++u) {
    int t = tid + 1024 * u;
    val[u] = (t < 2080);
    int tt = val[u] ? t : 2079;
    int k = (int)(64.5f - sqrtf(64.5f * 64.5f - 2.0f * (float)tt));
    k = k < 0 ? 0 : (k > 63 ? 63 : k);
    while (k < 63 && (64 * (k + 1) - (((k + 1) * k) >> 1)) <= tt) ++k;
    while (k > 0 && (64 * k - ((k * (k - 1)) >> 1)) > tt) --k;
    int mm = k + (tt - (64 * k - ((k * (k - 1)) >> 1)));
    ka[u] = k; ma[u] = mm;
    // positions at round 0: pair k = positions (k, 127-k)
    pk[u] = k; qk[u] = 127 - k; pm[u] = mm; qm[u] = 127 - mm;
  }
  int rp = tid, rq = 127 - tid;  // rotation-phase positions (tid<64)
  __syncthreads();

  for (int step = 0; step < NSTEPS; ++step) {
    if (tid < 64) {
      int p = rp, q = rq;
      float app = A[rb[p] + p];
      float aqq = A[rb[q] + q];
      int a_ = p < q ? p : q, b_ = p < q ? q : p;
      float apq = A[rb[a_] + b_];
      float c = 1.f, s = 0.f;
      if (fabsf(apq) > 1e-7f) {
        float tau = (aqq - app) / (2.f * apq);
        float tv = 1.f / (fabsf(tau) + sqrtf(1.f + tau * tau));
        tv = tau < 0.f ? -tv : tv;
        c = 1.f / sqrtf(1.f + tv * tv);
        s = tv * c;
      }
      cs[tid] = c; sn[tid] = s;
      rot[((size_t)m * NSTEPS + step) * 64 + tid] = make_float2(c, s);
    }
    __syncthreads();
#pragma unroll
    for (int u = 0; u < 3; ++u) {
      if (val[u]) {
        int Pk = pk[u], Qk = qk[u], Pm = pm[u], Qm = qm[u];
        float ck = cs[ka[u]], sk = sn[ka[u]];
        float cm = cs[ma[u]], sm = sn[ma[u]];
        int iA, iB;
        iA = Pk < Pm ? Pk : Pm; iB = Pk < Pm ? Pm : Pk; int x00 = rb[iA] + iB;
        iA = Pk < Qm ? Pk : Qm; iB = Pk < Qm ? Qm : Pk; int x01 = rb[iA] + iB;
        iA = Qk < Pm ? Qk : Pm; iB = Qk < Pm ? Pm : Qk; int x10 = rb[iA] + iB;
        iA = Qk < Qm ? Qk : Qm; iB = Qk < Qm ? Qm : Qk; int x11 = rb[iA] + iB;
        float a00 = A[x00], a01 = A[x01], a10 = A[x10], a11 = A[x11];
        // right-multiply by J_mm (column op), then left by J_k^T (row op)
        float b00 = cm * a00 - sm * a01, b01 = sm * a00 + cm * a01;
        float b10 = cm * a10 - sm * a11, b11 = sm * a10 + cm * a11;
        float n00 = ck * b00 - sk * b10, n01 = ck * b01 - sk * b11;
        float n10 = sk * b00 + ck * b10, n11 = sk * b01 + ck * b11;
        if (ka[u] == ma[u]) {
          A[x00] = n00;   // (Pk,Pk) diagonal
          A[x11] = n11;   // (Qk,Qk) diagonal
          A[x01] = 0.f;   // zeroed pivot (x01 == x10 slot)
        } else {
          A[x00] = n00; A[x01] = n01; A[x10] = n10; A[x11] = n11;
        }
      }
    }
    __syncthreads();
    rp = pstep(rp); rq = pstep(rq);
#pragma unroll
    for (int u = 0; u < 3; ++u) {
      pk[u] = pstep(pk[u]); qk[u] = pstep(qk[u]);
      pm[u] = pstep(pm[u]); qm[u] = pstep(qm[u]);
    }
  }

  // rank of each eigenvalue (descending, index tie-break) -> keep rank < 64
  if (tid < 128) {
    float di = A[rb[tid] + tid];
    int cnt = 0;
    for (int j = 0; j < 128; ++j) {
      float dj = A[rb[j] + j];
      cnt += ((dj > di) || (dj == di && j < tid)) ? 1 : 0;
    }
    rank[m * 128 + tid] = cnt;
  }
}

// ---------------- K3: replay rotations onto V = I, emit top-64 rows --------
// Split by 32-row chunks (4 chunks x 64 matrices = 256 blocks). V chunk held
// column-major with stride 44 (16B-aligned float4, banks spread by 44%32=12).
__global__ __launch_bounds__(256) void vapply_k(const float2* __restrict__ rot,
                                                const int* __restrict__ rank,
                                                float* __restrict__ Vt) {
  const int m = blockIdx.y;
  const int r0 = blockIdx.x * 32;
  const int tid = threadIdx.x;
  __shared__ __align__(16) float Vc[128 * 44];  // [col][row_local], 22.5 KB
  __shared__ int rkL[128];

  for (int t = tid; t < 128 * 32; t += 256) {
    int j = t >> 5, i = t & 31;
    Vc[j * 44 + i] = (j == r0 + i) ? 1.f : 0.f;
  }
  if (tid < 128) rkL[tid] = rank[m * 128 + tid];

  const int k0 = tid >> 3;   // pair 0..31
  const int k1 = k0 + 32;    // pair 32..63
  const int g = tid & 7;     // float4 row-group 0..7
  int p0 = k0, q0 = 127 - k0, p1 = k1, q1 = 127 - k1;
  const float2* rm = rot + (size_t)m * NSTEPS * 64;
  float2 c0 = rm[k0], c1 = rm[k1];

  for (int step = 0; step < NSTEPS; ++step) {
    float2 n0 = make_float2(1.f, 0.f), n1 = make_float2(1.f, 0.f);
    if (step + 1 < NSTEPS) {  // prefetch next step's rotations
      n0 = rm[(size_t)(step + 1) * 64 + k0];
      n1 = rm[(size_t)(step + 1) * 64 + k1];
    }
    __syncthreads();
    {
      float4 vp = *(float4*)&Vc[p0 * 44 + 4 * g];
      float4 vq = *(float4*)&Vc[q0 * 44 + 4 * g];
      float4 np, nq;
      np.x = c0.x * vp.x - c0.y * vq.x;  nq.x = c0.y * vp.x + c0.x * vq.x;
      np.y = c0.x * vp.y - c0.y * vq.y;  nq.y = c0.y * vp.y + c0.x * vq.y;
      np.z = c0.x * vp.z - c0.y * vq.z;  nq.z = c0.y * vp.z + c0.x * vq.z;
      np.w = c0.x * vp.w - c0.y * vq.w;  nq.w = c0.y * vp.w + c0.x * vq.w;
      *(float4*)&Vc[p0 * 44 + 4 * g] = np;
      *(float4*)&Vc[q0 * 44 + 4 * g] = nq;
    }
    {
      float4 vp = *(float4*)&Vc[p1 * 44 + 4 * g];
      float4 vq = *(float4*)&Vc[q1 * 44 + 4 * g];
      float4 np, nq;
      np.x = c1.x * vp.x - c1.y * vq.x;  nq.x = c1.y * vp.x + c1.x * vq.x;
      np.y = c1.x * vp.y - c1.y * vq.y;  nq.y = c1.y * vp.y + c1.x * vq.y;
      np.z = c1.x * vp.z - c1.y * vq.z;  nq.z = c1.y * vp.z + c1.x * vq.z;
      np.w = c1.x * vp.w - c1.y * vq.w;  nq.w = c1.y * vp.w + c1.x * vq.w;
      *(float4*)&Vc[p1 * 44 + 4 * g] = np;
      *(float4*)&Vc[q1 * 44 + 4 * g] = nq;
    }
    p0 = pstep(p0); q0 = pstep(q0); p1 = pstep(p1); q1 = pstep(q1);
    c0 = n0; c1 = n1;
  }
  __syncthreads();
  // eigenvector = column j of V; keep if rank<64, as row rk of Vt[m]
  for (int t = tid; t < 128 * 32; t += 256) {
    int j = t >> 5, i = t & 31;
    int rk = rkL[j];
    if (rk < RR) Vt[((size_t)m * RR + rk) * DD + (r0 + i)] = Vc[j * 44 + i];
  }
}

// ---------------- K4: W = X @ Vt^T  (2048x64 per matrix) -------------------
__global__ __launch_bounds__(256) void gemm1_k(const float* __restrict__ X,
                                               const float* __restrict__ Vt,
                                               float* __restrict__ W) {
  const int m = blockIdx.y;
  const int s0 = blockIdx.x * 32;
  const int tid = threadIdx.x;
  __shared__ __align__(16) float VtT[128 * 68];  // [c][r], 34.8 KB
  __shared__ __align__(16) float Xs[32 * 132];   // padded, 16.9 KB
  const float* Vm = Vt + (size_t)m * RR * DD;
  for (int t = tid; t < RR * DD; t += 256) {
    int r = t >> 7, c = t & 127;
    VtT[c * 68 + r] = Vm[t];
  }
  const float* Xm = X + ((size_t)m * SEQ + s0) * DD;
  for (int t = tid; t < 1024; t += 256) {  // 32 rows x 32 float4
    int s = t >> 5, c4 = t & 31;
    *(float4*)&Xs[s * 132 + 4 * c4] = *(const float4*)&Xm[(size_t)s * DD + 4 * c4];
  }
  __syncthreads();
  const int ti = tid >> 4;  // 0..15 -> rows 2ti, 2ti+1
  const int tj = tid & 15;  // cols 4tj..+3
  float acc[2][4] = {{0.f, 0.f, 0.f, 0.f}, {0.f, 0.f, 0.f, 0.f}};
#pragma unroll 4
  for (int k = 0; k < DD; ++k) {
    float a0 = Xs[(2 * ti) * 132 + k];
    float a1 = Xs[(2 * ti + 1) * 132 + k];
    float4 bv = *(float4*)&VtT[k * 68 + 4 * tj];
    acc[0][0] += a0 * bv.x; acc[0][1] += a0 * bv.y;
    acc[0][2] += a0 * bv.z; acc[0][3] += a0 * bv.w;
    acc[1][0] += a1 * bv.x; acc[1][1] += a1 * bv.y;
    acc[1][2] += a1 * bv.z; acc[1][3] += a1 * bv.w;
  }
  float* Wm = W + ((size_t)m * SEQ + s0) * RR;
#pragma unroll
  for (int d = 0; d < 2; ++d) {
    float4 v = make_float4(acc[d][0], acc[d][1], acc[d][2], acc[d][3]);
    *(float4*)&Wm[(size_t)(2 * ti + d) * RR + 4 * tj] = v;
  }
}

// ---------------- K5: out = W @ Vt  (2048x128 per matrix) ------------------
__global__ __launch_bounds__(256) void gemm2_k(const float* __restrict__ W,
                                               const float* __restrict__ Vt,
                                               float* __restrict__ out) {
  const int m = blockIdx.y;
  const int s0 = blockIdx.x * 32;
  const int tid = threadIdx.x;
  __shared__ __align__(16) float Vts[64 * 132];  // 33.8 KB
  __shared__ __align__(16) float Ws[32 * 68];    // 8.7 KB
  const float* Vm = Vt + (size_t)m * RR * DD;
  for (int t = tid; t < 2048; t += 256) {  // 64 rows x 32 float4
    int r = t >> 5, c4 = t & 31;
    *(float4*)&Vts[r * 132 + 4 * c4] = *(const float4*)&Vm[(size_t)r * DD + 4 * c4];
  }
  const float* Wm = W + ((size_t)m * SEQ + s0) * RR;
  for (int t = tid; t < 512; t += 256) {  // 32 rows x 16 float4
    int s = t >> 4, c4 = t & 15;
    *(float4*)&Ws[s * 68 + 4 * c4] = *(const float4*)&Wm[(size_t)s * RR + 4 * c4];
  }
  __syncthreads();
  const int ti = tid >> 5;  // 0..7 -> rows 4ti..+3
  const int tj = tid & 31;  // cols 4tj..+3
  float acc[4][4] = {{0.f,0.f,0.f,0.f},{0.f,0.f,0.f,0.f},
                     {0.f,0.f,0.f,0.f},{0.f,0.f,0.f,0.f}};
#pragma unroll 4
  for (int k = 0; k < RR; ++k) {
    float4 bv = *(float4*)&Vts[k * 132 + 4 * tj];
    float a0 = Ws[(4 * ti + 0) * 68 + k];
    float a1 = Ws[(4 * ti + 1) * 68 + k];
    float a2 = Ws[(4 * ti + 2) * 68 + k];
    float a3 = Ws[(4 * ti + 3) * 68 + k];
    acc[0][0] += a0 * bv.x; acc[0][1] += a0 * bv.y;
    acc[0][2] += a0 * bv.z; acc[0][3] += a0 * bv.w;
    acc[1][0] += a1 * bv.x; acc[1][1] += a1 * bv.y;
    acc[1][2] += a1 * bv.z; acc[1][3] += a1 * bv.w;
    acc[2][0] += a2 * bv.x; acc[2][1] += a2 * bv.y;
    acc[2][2] += a2 * bv.z; acc[2][3] += a2 * bv.w;
    acc[3][0] += a3 * bv.x; acc[3][1] += a3 * bv.y;
    acc[3][2] += a3 * bv.z; acc[3][3] += a3 * bv.w;
  }
  float* Om = out + ((size_t)m * SEQ + s0) * DD;
#pragma unroll
  for (int d = 0; d < 4; ++d) {
    float4 v = make_float4(acc[d][0], acc[d][1], acc[d][2], acc[d][3]);
    *(float4*)&Om[(size_t)(4 * ti + d) * DD + 4 * tj] = v;
  }
}

extern "C" void kernel_launch(void* const* d_in, const int* in_sizes, int n_in,
                              void* d_out, int out_size, void* d_ws, size_t ws_size,
                              hipStream_t stream) {
  (void)in_sizes; (void)n_in; (void)out_size; (void)ws_size;
  const float* X = (const float*)d_in[0];  // rank (d_in[1]) is fixed at 64
  float* out = (float*)d_out;
  char* ws = (char*)d_ws;
  float* G = (float*)ws;
  float2* rot = (float2*)(ws + OFF_ROT);
  int* rank = (int*)(ws + OFF_RANK);
  float* Vt = (float*)(ws + OFF_VT);
  float* W = (float*)ws;  // overlays G+rot, both dead by the time W is written

  gram_k<<<dim3(4, NM), 256, 0, stream>>>(X, G);
  jacobi_k<<<NM, 1024, 0, stream>>>(G, rot, rank);
  vapply_k<<<dim3(4, NM), 256, 0, stream>>>(rot, rank, Vt);
  gemm1_k<<<dim3(SEQ / 32, NM), 256, 0, stream>>>(X, Vt, W);
  gemm2_k<<<dim3(SEQ / 32, NM), 256, 0, stream>>>(W, Vt, out);
}

// Round 3
// 1965.371 us; speedup vs baseline: 2.1909x; 1.2147x over previous
//
#include <hip/hip_runtime.h>

// LowRankKVCache: out = X @ Vt^T @ Vt where Vt = top-64 eigenvectors of X^T X.
// 64 independent 2048x128 fp32 matrices (B*H = 4*16).
//
// ws layout (bytes):
//   [0, 4.19M)           G     (64 x 128x128 f32)        -- dead after jacobi_k
//   [4.19M, 33.33M)      rot   (64 x NSTEPS x 64 float2) -- dead after vapply_k
//   [33.55M, 33.59M)     rank  (64 x 128 int)            -- above W overlay
//   [33.59M, 35.68M)     Vt    (64 x 64x128 f32)
//   [0, 33.55M)          W     (64 x 2048x64 f32)        -- overlays dead G+rot
// total requirement: ~36 MB of d_ws.

#define NM 64
#define SEQ 2048
#define DD 128
#define RR 64
#define NSWEEP 7
#define NSTEPS (NSWEEP * 127)

#define OFF_ROT  (4194304ULL)
#define OFF_RANK (33554432ULL)          // == W end; survives gemm1/gemm2
#define OFF_VT   (OFF_RANK + 32768ULL)

// round-robin tournament position advance: position 0 fixed, others rotate.
__device__ __forceinline__ int pstep(int p) {
  return p == 0 ? 0 : (p == 127 ? 1 : p + 1);
}
// packed upper-triangle addressing, computed in VALU (rb[] LDS reads cost
// 4 of 16 LDS instrs/item in round 2 -- arithmetic is ~3 VALU ops, VALU idle)
__device__ __forceinline__ int rbase(int i) { return (i * (255 - i)) >> 1; }
__device__ __forceinline__ int pidx(int i, int j) {
  int a = i < j ? i : j;
  int b = i ^ j ^ a;
  return ((a * (255 - a)) >> 1) + b;
}

// ---------------- K1: Gram G[m] = X[m]^T X[m] ----------------
__global__ __launch_bounds__(256) void gram_k(const float* __restrict__ X,
                                              float* __restrict__ G) {
  const int m = blockIdx.y;
  const int r0 = blockIdx.x * 32;  // G row tile (== X column tile)
  const int tid = threadIdx.x;
  __shared__ __align__(16) float Xs[64][128];  // 32 KB
  const float* Xm = X + (size_t)m * SEQ * DD;
  const int ti = tid >> 5;  // 0..7  -> G rows r0+4ti..+3
  const int tj = tid & 31;  // 0..31 -> G cols 4tj..+3
  float acc[4][4];
#pragma unroll
  for (int a = 0; a < 4; ++a)
#pragma unroll
    for (int b = 0; b < 4; ++b) acc[a][b] = 0.f;

  for (int s0 = 0; s0 < SEQ; s0 += 64) {
    __syncthreads();
    for (int t = tid; t < 2048; t += 256) {  // 64 rows x 32 float4
      int s = t >> 5, c4 = t & 31;
      *(float4*)&Xs[s][c4 * 4] =
          *(const float4*)&Xm[(size_t)(s0 + s) * DD + c4 * 4];
    }
    __syncthreads();
#pragma unroll 4
    for (int s = 0; s < 64; ++s) {
      float4 av = *(const float4*)&Xs[s][r0 + 4 * ti];
      float4 bv = *(const float4*)&Xs[s][4 * tj];
      acc[0][0] += av.x * bv.x; acc[0][1] += av.x * bv.y;
      acc[0][2] += av.x * bv.z; acc[0][3] += av.x * bv.w;
      acc[1][0] += av.y * bv.x; acc[1][1] += av.y * bv.y;
      acc[1][2] += av.y * bv.z; acc[1][3] += av.y * bv.w;
      acc[2][0] += av.z * bv.x; acc[2][1] += av.z * bv.y;
      acc[2][2] += av.z * bv.z; acc[2][3] += av.z * bv.w;
      acc[3][0] += av.w * bv.x; acc[3][1] += av.w * bv.y;
      acc[3][2] += av.w * bv.z; acc[3][3] += av.w * bv.w;
    }
  }
  float* Gm = G + (size_t)m * DD * DD;
#pragma unroll
  for (int a = 0; a < 4; ++a) {
    float4 v = make_float4(acc[a][0], acc[a][1], acc[a][2], acc[a][3]);
    *(float4*)&Gm[(size_t)(r0 + 4 * ti + a) * DD + 4 * tj] = v;
  }
}

// ---------------- K2: parallel Jacobi eigensolver on packed symmetric A ----
// One block (1024 threads, 16 waves) per matrix. Packed upper triangle
// (8256 f32, 33 KB). Per step: 64 disjoint rotations; each unordered
// pair-of-pairs item owns a 2x2 block exclusively (hazard-free in-place).
// Round-3 changes: rb[] lookups -> VALU arithmetic; (c,s) as float2 b64
// reads; threshold-Jacobi identity skip (exact) culls late-sweep items.
__global__ __launch_bounds__(1024) void jacobi_k(const float* __restrict__ G,
                                                 float2* __restrict__ rot,
                                                 int* __restrict__ rank) {
  const int m = blockIdx.x;
  const int tid = threadIdx.x;
  __shared__ float A[8256];
  __shared__ float2 cs2[64];
  const float* Gm = G + (size_t)m * DD * DD;

  for (int t = tid; t < DD * DD; t += 1024) {
    int i = t >> 7, j = t & 127;
    if (j >= i) A[rbase(i) + j] = Gm[t];
  }

  // Per-thread static item list over 2080 unordered pair-pairs (k<=mm).
  int ka[3], ma[3], pk[3], qk[3], pm[3], qm[3];
  bool val[3];
#pragma unroll
  for (int u = 0; u < 3; ++u) {
    int t = tid + 1024 * u;
    val[u] = (t < 2080);
    int tt = val[u] ? t : 2079;
    int k = (int)(64.5f - sqrtf(64.5f * 64.5f - 2.0f * (float)tt));
    k = k < 0 ? 0 : (k > 63 ? 63 : k);
    while (k < 63 && (64 * (k + 1) - (((k + 1) * k) >> 1)) <= tt) ++k;
    while (k > 0 && (64 * k - ((k * (k - 1)) >> 1)) > tt) --k;
    int mm = k + (tt - (64 * k - ((k * (k - 1)) >> 1)));
    ka[u] = k; ma[u] = mm;
    pk[u] = k; qk[u] = 127 - k; pm[u] = mm; qm[u] = 127 - mm;
  }
  int rp = tid, rq = 127 - tid;  // rotation-phase positions (tid<64)
  __syncthreads();

  for (int step = 0; step < NSTEPS; ++step) {
    if (tid < 64) {
      int p = rp, q = rq;
      float app = A[rbase(p) + p];
      float aqq = A[rbase(q) + q];
      float apq = A[pidx(p, q)];
      float c = 1.f, s = 0.f;
      // threshold-Jacobi: |apq| <~ 3e-5 * sqrt(|app*aqq|) -> exact identity
      if (apq * apq > 1e-9f * fabsf(app * aqq) + 1e-30f) {
        float tau = (aqq - app) / (2.f * apq);
        float tv = 1.f / (fabsf(tau) + sqrtf(1.f + tau * tau));
        tv = tau < 0.f ? -tv : tv;
        c = 1.f / sqrtf(1.f + tv * tv);
        s = tv * c;
      }
      float2 r2 = make_float2(c, s);
      cs2[tid] = r2;
      rot[((size_t)m * NSTEPS + step) * 64 + tid] = r2;
    }
    __syncthreads();
#pragma unroll
    for (int u = 0; u < 3; ++u) {
      if (val[u]) {
        float2 Rk = cs2[ka[u]];
        float2 Rm = cs2[ma[u]];
        if ((Rk.y != 0.f) || (Rm.y != 0.f)) {  // skip == exact identity
          int x00 = pidx(pk[u], pm[u]);
          int x01 = pidx(pk[u], qm[u]);
          int x10 = pidx(qk[u], pm[u]);
          int x11 = pidx(qk[u], qm[u]);
          float a00 = A[x00], a01 = A[x01], a10 = A[x10], a11 = A[x11];
          float ck = Rk.x, sk = Rk.y, cm = Rm.x, sm = Rm.y;
          // right-multiply by J_mm (column op), then left by J_k^T (row op)
          float b00 = cm * a00 - sm * a01, b01 = sm * a00 + cm * a01;
          float b10 = cm * a10 - sm * a11, b11 = sm * a10 + cm * a11;
          float n00 = ck * b00 - sk * b10, n01 = ck * b01 - sk * b11;
          float n10 = sk * b00 + ck * b10, n11 = sk * b01 + ck * b11;
          if (ka[u] == ma[u]) {
            A[x00] = n00;   // (Pk,Pk) diagonal
            A[x11] = n11;   // (Qk,Qk) diagonal
            A[x01] = 0.f;   // zeroed pivot (x01 == x10 slot)
          } else {
            A[x00] = n00; A[x01] = n01; A[x10] = n10; A[x11] = n11;
          }
        }
      }
    }
    __syncthreads();
    rp = pstep(rp); rq = pstep(rq);
#pragma unroll
    for (int u = 0; u < 3; ++u) {
      pk[u] = pstep(pk[u]); qk[u] = pstep(qk[u]);
      pm[u] = pstep(pm[u]); qm[u] = pstep(qm[u]);
    }
  }

  // rank of each eigenvalue (descending, index tie-break) -> keep rank < 64
  if (tid < 128) {
    float di = A[rbase(tid) + tid];
    int cnt = 0;
    for (int j = 0; j < 128; ++j) {
      float dj = A[rbase(j) + j];
      cnt += ((dj > di) || (dj == di && j < tid)) ? 1 : 0;
    }
    rank[m * 128 + tid] = cnt;
  }
}

// ---------------- K3: replay rotations onto V = I, emit top-64 rows --------
// Split by 32-row chunks (4 chunks x 64 matrices = 256 blocks). V chunk held
// column-major with stride 44 (16B-aligned float4, banks spread by 44%32=12).
__global__ __launch_bounds__(256) void vapply_k(const float2* __restrict__ rot,
                                                const int* __restrict__ rank,
                                                float* __restrict__ Vt) {
  const int m = blockIdx.y;
  const int r0 = blockIdx.x * 32;
  const int tid = threadIdx.x;
  __shared__ __align__(16) float Vc[128 * 44];  // [col][row_local], 22.5 KB
  __shared__ int rkL[128];

  for (int t = tid; t < 128 * 32; t += 256) {
    int j = t >> 5, i = t & 31;
    Vc[j * 44 + i] = (j == r0 + i) ? 1.f : 0.f;
  }
  if (tid < 128) rkL[tid] = rank[m * 128 + tid];

  const int k0 = tid >> 3;   // pair 0..31
  const int k1 = k0 + 32;    // pair 32..63
  const int g = tid & 7;     // float4 row-group 0..7
  int p0 = k0, q0 = 127 - k0, p1 = k1, q1 = 127 - k1;
  const float2* rm = rot + (size_t)m * NSTEPS * 64;
  float2 c0 = rm[k0], c1 = rm[k1];

  for (int step = 0; step < NSTEPS; ++step) {
    float2 n0 = make_float2(1.f, 0.f), n1 = make_float2(1.f, 0.f);
    if (step + 1 < NSTEPS) {  // prefetch next step's rotations
      n0 = rm[(size_t)(step + 1) * 64 + k0];
      n1 = rm[(size_t)(step + 1) * 64 + k1];
    }
    __syncthreads();
    if (c0.y != 0.f) {  // identity rotations skip exactly
      float4 vp = *(float4*)&Vc[p0 * 44 + 4 * g];
      float4 vq = *(float4*)&Vc[q0 * 44 + 4 * g];
      float4 np, nq;
      np.x = c0.x * vp.x - c0.y * vq.x;  nq.x = c0.y * vp.x + c0.x * vq.x;
      np.y = c0.x * vp.y - c0.y * vq.y;  nq.y = c0.y * vp.y + c0.x * vq.y;
      np.z = c0.x * vp.z - c0.y * vq.z;  nq.z = c0.y * vp.z + c0.x * vq.z;
      np.w = c0.x * vp.w - c0.y * vq.w;  nq.w = c0.y * vp.w + c0.x * vq.w;
      *(float4*)&Vc[p0 * 44 + 4 * g] = np;
      *(float4*)&Vc[q0 * 44 + 4 * g] = nq;
    }
    if (c1.y != 0.f) {
      float4 vp = *(float4*)&Vc[p1 * 44 + 4 * g];
      float4 vq = *(float4*)&Vc[q1 * 44 + 4 * g];
      float4 np, nq;
      np.x = c1.x * vp.x - c1.y * vq.x;  nq.x = c1.y * vp.x + c1.x * vq.x;
      np.y = c1.x * vp.y - c1.y * vq.y;  nq.y = c1.y * vp.y + c1.x * vq.y;
      np.z = c1.x * vp.z - c1.y * vq.z;  nq.z = c1.y * vp.z + c1.x * vq.z;
      np.w = c1.x * vp.w - c1.y * vq.w;  nq.w = c1.y * vp.w + c1.x * vq.w;
      *(float4*)&Vc[p1 * 44 + 4 * g] = np;
      *(float4*)&Vc[q1 * 44 + 4 * g] = nq;
    }
    p0 = pstep(p0); q0 = pstep(q0); p1 = pstep(p1); q1 = pstep(q1);
    c0 = n0; c1 = n1;
  }
  __syncthreads();
  // eigenvector = column j of V; keep if rank<64, as row rk of Vt[m]
  for (int t = tid; t < 128 * 32; t += 256) {
    int j = t >> 5, i = t & 31;
    int rk = rkL[j];
    if (rk < RR) Vt[((size_t)m * RR + rk) * DD + (r0 + i)] = Vc[j * 44 + i];
  }
}

// ---------------- K4: W = X @ Vt^T  (2048x64 per matrix) -------------------
__global__ __launch_bounds__(256) void gemm1_k(const float* __restrict__ X,
                                               const float* __restrict__ Vt,
                                               float* __restrict__ W) {
  const int m = blockIdx.y;
  const int s0 = blockIdx.x * 32;
  const int tid = threadIdx.x;
  __shared__ __align__(16) float VtT[128 * 68];  // [c][r], 34.8 KB
  __shared__ __align__(16) float Xs[32 * 132];   // padded, 16.9 KB
  const float* Vm = Vt + (size_t)m * RR * DD;
  for (int t = tid; t < RR * DD; t += 256) {
    int r = t >> 7, c = t & 127;
    VtT[c * 68 + r] = Vm[t];
  }
  const float* Xm = X + ((size_t)m * SEQ + s0) * DD;
  for (int t = tid; t < 1024; t += 256) {  // 32 rows x 32 float4
    int s = t >> 5, c4 = t & 31;
    *(float4*)&Xs[s * 132 + 4 * c4] = *(const float4*)&Xm[(size_t)s * DD + 4 * c4];
  }
  __syncthreads();
  const int ti = tid >> 4;  // 0..15 -> rows 2ti, 2ti+1
  const int tj = tid & 15;  // cols 4tj..+3
  float acc[2][4] = {{0.f, 0.f, 0.f, 0.f}, {0.f, 0.f, 0.f, 0.f}};
#pragma unroll 4
  for (int k = 0; k < DD; ++k) {
    float a0 = Xs[(2 * ti) * 132 + k];
    float a1 = Xs[(2 * ti + 1) * 132 + k];
    float4 bv = *(float4*)&VtT[k * 68 + 4 * tj];
    acc[0][0] += a0 * bv.x; acc[0][1] += a0 * bv.y;
    acc[0][2] += a0 * bv.z; acc[0][3] += a0 * bv.w;
    acc[1][0] += a1 * bv.x; acc[1][1] += a1 * bv.y;
    acc[1][2] += a1 * bv.z; acc[1][3] += a1 * bv.w;
  }
  float* Wm = W + ((size_t)m * SEQ + s0) * RR;
#pragma unroll
  for (int d = 0; d < 2; ++d) {
    float4 v = make_float4(acc[d][0], acc[d][1], acc[d][2], acc[d][3]);
    *(float4*)&Wm[(size_t)(2 * ti + d) * RR + 4 * tj] = v;
  }
}

// ---------------- K5: out = W @ Vt  (2048x128 per matrix) ------------------
__global__ __launch_bounds__(256) void gemm2_k(const float* __restrict__ W,
                                               const float* __restrict__ Vt,
                                               float* __restrict__ out) {
  const int m = blockIdx.y;
  const int s0 = blockIdx.x * 32;
  const int tid = threadIdx.x;
  __shared__ __align__(16) float Vts[64 * 132];  // 33.8 KB
  __shared__ __align__(16) float Ws[32 * 68];    // 8.7 KB
  const float* Vm = Vt + (size_t)m * RR * DD;
  for (int t = tid; t < 2048; t += 256) {  // 64 rows x 32 float4
    int r = t >> 5, c4 = t & 31;
    *(float4*)&Vts[r * 132 + 4 * c4] = *(const float4*)&Vm[(size_t)r * DD + 4 * c4];
  }
  const float* Wm = W + ((size_t)m * SEQ + s0) * RR;
  for (int t = tid; t < 512; t += 256) {  // 32 rows x 16 float4
    int s = t >> 4, c4 = t & 15;
    *(float4*)&Ws[s * 68 + 4 * c4] = *(const float4*)&Wm[(size_t)s * RR + 4 * c4];
  }
  __syncthreads();
  const int ti = tid >> 5;  // 0..7 -> rows 4ti..+3
  const int tj = tid & 31;  // cols 4tj..+3
  float acc[4][4] = {{0.f,0.f,0.f,0.f},{0.f,0.f,0.f,0.f},
                     {0.f,0.f,0.f,0.f},{0.f,0.f,0.f,0.f}};
#pragma unroll 4
  for (int k = 0; k < RR; ++k) {
    float4 bv = *(float4*)&Vts[k * 132 + 4 * tj];
    float a0 = Ws[(4 * ti + 0) * 68 + k];
    float a1 = Ws[(4 * ti + 1) * 68 + k];
    float a2 = Ws[(4 * ti + 2) * 68 + k];
    float a3 = Ws[(4 * ti + 3) * 68 + k];
    acc[0][0] += a0 * bv.x; acc[0][1] += a0 * bv.y;
    acc[0][2] += a0 * bv.z; acc[0][3] += a0 * bv.w;
    acc[1][0] += a1 * bv.x; acc[1][1] += a1 * bv.y;
    acc[1][2] += a1 * bv.z; acc[1][3] += a1 * bv.w;
    acc[2][0] += a2 * bv.x; acc[2][1] += a2 * bv.y;
    acc[2][2] += a2 * bv.z; acc[2][3] += a2 * bv.w;
    acc[3][0] += a3 * bv.x; acc[3][1] += a3 * bv.y;
    acc[3][2] += a3 * bv.z; acc[3][3] += a3 * bv.w;
  }
  float* Om = out + ((size_t)m * SEQ + s0) * DD;
#pragma unroll
  for (int d = 0; d < 4; ++d) {
    float4 v = make_float4(acc[d][0], acc[d][1], acc[d][2], acc[d][3]);
    *(float4*)&Om[(size_t)(4 * ti + d) * DD + 4 * tj] = v;
  }
}

extern "C" void kernel_launch(void* const* d_in, const int* in_sizes, int n_in,
                              void* d_out, int out_size, void* d_ws, size_t ws_size,
                              hipStream_t stream) {
  (void)in_sizes; (void)n_in; (void)out_size; (void)ws_size;
  const float* X = (const float*)d_in[0];  // rank (d_in[1]) is fixed at 64
  float* out = (float*)d_out;
  char* ws = (char*)d_ws;
  float* G = (float*)ws;
  float2* rot = (float2*)(ws + OFF_ROT);
  int* rank = (int*)(ws + OFF_RANK);
  float* Vt = (float*)(ws + OFF_VT);
  float* W = (float*)ws;  // overlays G+rot, both dead by the time W is written

  gram_k<<<dim3(4, NM), 256, 0, stream>>>(X, G);
  jacobi_k<<<NM, 1024, 0, stream>>>(G, rot, rank);
  vapply_k<<<dim3(4, NM), 256, 0, stream>>>(rot, rank, Vt);
  gemm1_k<<<dim3(SEQ / 32, NM), 256, 0, stream>>>(X, Vt, W);
  gemm2_k<<<dim3(SEQ / 32, NM), 256, 0, stream>>>(W, Vt, out);
}

// Round 4
// 1367.595 us; speedup vs baseline: 3.1485x; 1.4371x over previous
//
#include <hip/hip_runtime.h>

// LowRankKVCache: out = X @ Vt^T @ Vt where Vt = top-64 eigenvectors of X^T X.
// 64 independent 2048x128 fp32 matrices (B*H = 4*16).
//
// Round 4: one-sided Jacobi on G (== two-sided on G^2, same eigenvectors).
// Columns of the rotated G converge to lambda_j * v_j: eigenvectors fall out
// directly (no rotation log, no vapply replay). One barrier per step, no
// serial rotation phase (DPP butterfly reductions in the VALU pipe).
//
// ws layout (bytes):
//   [0, 4M)        G      (64 x 128x128 f32)   -- dead after jacobi1s_k
//   [4M, 8M)       Vfull  (64 x 128x128 f32)   -- dead after select_k
//   [8M, 8M+32K)   normg  (64 x 128 f32)       -- dead after select_k
//   [32M, 34M)     Vt     (64 x 64x128 f32)
//   [0, 32M)       W      (64 x 2048x64 f32)   -- overlays dead G/Vfull/normg
// total requirement: 34 MB of d_ws.

#define NM 64
#define SEQ 2048
#define DD 128
#define RR 64
#define NSWEEP 7
#define NSTEPS (NSWEEP * 127)

#define OFF_VFULL (4194304ULL)
#define OFF_NORM  (8388608ULL)
#define OFF_VT    (33554432ULL)

// round-robin tournament position advance: position 0 fixed, others rotate.
__device__ __forceinline__ int pstep(int p) {
  return p == 0 ? 0 : (p == 127 ? 1 : p + 1);
}

__device__ __forceinline__ float dot4(float4 a, float4 b) {
  return a.x * b.x + a.y * b.y + a.z * b.z + a.w * b.w;
}

// DPP butterfly add over aligned lane groups (VALU pipe -- keeps the DS pipe
// free for the column traffic). CTRL: 0xB1=quad xor1, 0x4E=quad xor2,
// 0x141=row_half_mirror (8-lane), 0x140=row_mirror (16-lane).
template <int CTRL>
__device__ __forceinline__ float dpp_add(float x) {
  int y = __builtin_amdgcn_update_dpp(0, __float_as_int(x), CTRL, 0xf, 0xf, true);
  return x + __int_as_float(y);
}
__device__ __forceinline__ float red16(float x) {  // sum over aligned 16 lanes
  x = dpp_add<0xB1>(x);
  x = dpp_add<0x4E>(x);
  x = dpp_add<0x141>(x);
  x = dpp_add<0x140>(x);
  return x;
}
__device__ __forceinline__ float red8(float x) {  // sum over aligned 8 lanes
  x = dpp_add<0xB1>(x);
  x = dpp_add<0x4E>(x);
  x = dpp_add<0x141>(x);
  return x;
}

// ---------------- K1: Gram G[m] = X[m]^T X[m] ----------------
__global__ __launch_bounds__(256) void gram_k(const float* __restrict__ X,
                                              float* __restrict__ G) {
  const int m = blockIdx.y;
  const int r0 = blockIdx.x * 32;  // G row tile (== X column tile)
  const int tid = threadIdx.x;
  __shared__ __align__(16) float Xs[64][128];  // 32 KB
  const float* Xm = X + (size_t)m * SEQ * DD;
  const int ti = tid >> 5;  // 0..7  -> G rows r0+4ti..+3
  const int tj = tid & 31;  // 0..31 -> G cols 4tj..+3
  float acc[4][4];
#pragma unroll
  for (int a = 0; a < 4; ++a)
#pragma unroll
    for (int b = 0; b < 4; ++b) acc[a][b] = 0.f;

  for (int s0 = 0; s0 < SEQ; s0 += 64) {
    __syncthreads();
    for (int t = tid; t < 2048; t += 256) {  // 64 rows x 32 float4
      int s = t >> 5, c4 = t & 31;
      *(float4*)&Xs[s][c4 * 4] =
          *(const float4*)&Xm[(size_t)(s0 + s) * DD + c4 * 4];
    }
    __syncthreads();
#pragma unroll 4
    for (int s = 0; s < 64; ++s) {
      float4 av = *(const float4*)&Xs[s][r0 + 4 * ti];
      float4 bv = *(const float4*)&Xs[s][4 * tj];
      acc[0][0] += av.x * bv.x; acc[0][1] += av.x * bv.y;
      acc[0][2] += av.x * bv.z; acc[0][3] += av.x * bv.w;
      acc[1][0] += av.y * bv.x; acc[1][1] += av.y * bv.y;
      acc[1][2] += av.y * bv.z; acc[1][3] += av.y * bv.w;
      acc[2][0] += av.z * bv.x; acc[2][1] += av.z * bv.y;
      acc[2][2] += av.z * bv.z; acc[2][3] += av.z * bv.w;
      acc[3][0] += av.w * bv.x; acc[3][1] += av.w * bv.y;
      acc[3][2] += av.w * bv.z; acc[3][3] += av.w * bv.w;
    }
  }
  float* Gm = G + (size_t)m * DD * DD;
#pragma unroll
  for (int a = 0; a < 4; ++a) {
    float4 v = make_float4(acc[a][0], acc[a][1], acc[a][2], acc[a][3]);
    *(float4*)&Gm[(size_t)(r0 + 4 * ti + a) * DD + 4 * tj] = v;
  }
}

// ---------------- K2: one-sided Jacobi on B = G (columns in LDS) -----------
// 1024 threads = 64 groups x 16 lanes; group g owns column pair (p,q).
// Groups touch disjoint columns each step -> one barrier per step.
// B col-major as float4: col j = B4[j*32 .. j*32+31]; 64 KB exactly.
// Lane l reads float4 idx l and 16+l of each column: 16 consecutive float4s
// per instr = contiguous 256B = conflict-free ds_read_b128.
__global__ __launch_bounds__(1024) void jacobi1s_k(const float* __restrict__ G,
                                                   float* __restrict__ Vfull,
                                                   float* __restrict__ normg) {
  const int m = blockIdx.x;
  const int tid = threadIdx.x;
  const int g = tid >> 4;  // pair group 0..63
  const int l = tid & 15;  // lane in group
  __shared__ float4 B4[DD * 32];  // 64 KB

  // G is symmetric: column j of G == row j of G -> transpose-free load.
  const float4* Gm4 = (const float4*)(G + (size_t)m * DD * DD);
  for (int t = tid; t < DD * 32; t += 1024) B4[t] = Gm4[t];

  int p = g, q = 127 - g;
  for (int step = 0; step < NSTEPS; ++step) {
    __syncthreads();
    float4 bp0 = B4[p * 32 + l];
    float4 bp1 = B4[p * 32 + 16 + l];
    float4 bq0 = B4[q * 32 + l];
    float4 bq1 = B4[q * 32 + 16 + l];
    // 2x2 Gram of the pair, reduced across the 16-lane group (VALU DPP).
    float app = red16(dot4(bp0, bp0) + dot4(bp1, bp1));
    float apq = red16(dot4(bp0, bq0) + dot4(bp1, bq1));
    float aqq = red16(dot4(bq0, bq0) + dot4(bq1, bq1));
    if (apq * apq > 1e-9f * app * aqq) {  // skip == exact identity rotation
      float tau = (aqq - app) / (2.f * apq);
      float tv = 1.f / (fabsf(tau) + sqrtf(1.f + tau * tau));
      tv = tau < 0.f ? -tv : tv;
      float c = 1.f / sqrtf(1.f + tv * tv);
      float s = tv * c;
      float4 np0, np1, nq0, nq1;
      np0.x = c * bp0.x - s * bq0.x;  nq0.x = s * bp0.x + c * bq0.x;
      np0.y = c * bp0.y - s * bq0.y;  nq0.y = s * bp0.y + c * bq0.y;
      np0.z = c * bp0.z - s * bq0.z;  nq0.z = s * bp0.z + c * bq0.z;
      np0.w = c * bp0.w - s * bq0.w;  nq0.w = s * bp0.w + c * bq0.w;
      np1.x = c * bp1.x - s * bq1.x;  nq1.x = s * bp1.x + c * bq1.x;
      np1.y = c * bp1.y - s * bq1.y;  nq1.y = s * bp1.y + c * bq1.y;
      np1.z = c * bp1.z - s * bq1.z;  nq1.z = s * bp1.z + c * bq1.z;
      np1.w = c * bp1.w - s * bq1.w;  nq1.w = s * bp1.w + c * bq1.w;
      B4[p * 32 + l] = np0;
      B4[p * 32 + 16 + l] = np1;
      B4[q * 32 + l] = nq0;
      B4[q * 32 + 16 + l] = nq1;
    }
    p = pstep(p);
    q = pstep(q);
  }
  __syncthreads();

  // Emit all 128 (unnormalized) eigenvector candidates + squared norms.
  // 8 threads per column: thread (j = tid>>3, sub = tid&7) handles rows
  // 16*sub .. 16*sub+15 (4 float4s).
  const int j = tid >> 3;
  const int sub = tid & 7;
  float4 v0 = B4[j * 32 + sub * 4 + 0];
  float4 v1 = B4[j * 32 + sub * 4 + 1];
  float4 v2 = B4[j * 32 + sub * 4 + 2];
  float4 v3 = B4[j * 32 + sub * 4 + 3];
  float nrm = red8(dot4(v0, v0) + dot4(v1, v1) + dot4(v2, v2) + dot4(v3, v3));
  float4* Vout = (float4*)(Vfull + ((size_t)m * DD + j) * DD) + sub * 4;
  Vout[0] = v0; Vout[1] = v1; Vout[2] = v2; Vout[3] = v3;
  if (sub == 0) normg[m * DD + j] = nrm;  // |col|^2 = lambda_j^2
}

// ---------------- K2b: rank-select top-64 columns, normalize -> Vt ---------
__global__ __launch_bounds__(128) void select_k(const float* __restrict__ Vfull,
                                                const float* __restrict__ normg,
                                                float* __restrict__ Vt) {
  const int m = blockIdx.x;
  const int t = threadIdx.x;  // 0..127
  __shared__ float n[DD];
  __shared__ int inv[RR];
  __shared__ float scl[RR];
  n[t] = normg[m * DD + t];
  __syncthreads();
  float nt = n[t];
  int rk = 0;
  for (int k = 0; k < DD; ++k) {
    float nk = n[k];
    rk += ((nk > nt) || (nk == nt && k < t)) ? 1 : 0;
  }
  if (rk < RR) { inv[rk] = t; scl[rk] = 1.f / sqrtf(nt); }
  __syncthreads();
  for (int r = 0; r < RR; ++r) {
    Vt[((size_t)m * RR + r) * DD + t] =
        Vfull[((size_t)m * DD + inv[r]) * DD + t] * scl[r];
  }
}

// ---------------- K4: W = X @ Vt^T  (2048x64 per matrix) -------------------
__global__ __launch_bounds__(256) void gemm1_k(const float* __restrict__ X,
                                               const float* __restrict__ Vt,
                                               float* __restrict__ W) {
  const int m = blockIdx.y;
  const int s0 = blockIdx.x * 32;
  const int tid = threadIdx.x;
  __shared__ __align__(16) float VtT[128 * 68];  // [c][r], 34.8 KB
  __shared__ __align__(16) float Xs[32 * 132];   // padded, 16.9 KB
  const float* Vm = Vt + (size_t)m * RR * DD;
  for (int t = tid; t < RR * DD; t += 256) {
    int r = t >> 7, c = t & 127;
    VtT[c * 68 + r] = Vm[t];
  }
  const float* Xm = X + ((size_t)m * SEQ + s0) * DD;
  for (int t = tid; t < 1024; t += 256) {  // 32 rows x 32 float4
    int s = t >> 5, c4 = t & 31;
    *(float4*)&Xs[s * 132 + 4 * c4] = *(const float4*)&Xm[(size_t)s * DD + 4 * c4];
  }
  __syncthreads();
  const int ti = tid >> 4;  // 0..15 -> rows 2ti, 2ti+1
  const int tj = tid & 15;  // cols 4tj..+3
  float acc[2][4] = {{0.f, 0.f, 0.f, 0.f}, {0.f, 0.f, 0.f, 0.f}};
#pragma unroll 4
  for (int k = 0; k < DD; ++k) {
    float a0 = Xs[(2 * ti) * 132 + k];
    float a1 = Xs[(2 * ti + 1) * 132 + k];
    float4 bv = *(float4*)&VtT[k * 68 + 4 * tj];
    acc[0][0] += a0 * bv.x; acc[0][1] += a0 * bv.y;
    acc[0][2] += a0 * bv.z; acc[0][3] += a0 * bv.w;
    acc[1][0] += a1 * bv.x; acc[1][1] += a1 * bv.y;
    acc[1][2] += a1 * bv.z; acc[1][3] += a1 * bv.w;
  }
  float* Wm = W + ((size_t)m * SEQ + s0) * RR;
#pragma unroll
  for (int d = 0; d < 2; ++d) {
    float4 v = make_float4(acc[d][0], acc[d][1], acc[d][2], acc[d][3]);
    *(float4*)&Wm[(size_t)(2 * ti + d) * RR + 4 * tj] = v;
  }
}

// ---------------- K5: out = W @ Vt  (2048x128 per matrix) ------------------
__global__ __launch_bounds__(256) void gemm2_k(const float* __restrict__ W,
                                               const float* __restrict__ Vt,
                                               float* __restrict__ out) {
  const int m = blockIdx.y;
  const int s0 = blockIdx.x * 32;
  const int tid = threadIdx.x;
  __shared__ __align__(16) float Vts[64 * 132];  // 33.8 KB
  __shared__ __align__(16) float Ws[32 * 68];    // 8.7 KB
  const float* Vm = Vt + (size_t)m * RR * DD;
  for (int t = tid; t < 2048; t += 256) {  // 64 rows x 32 float4
    int r = t >> 5, c4 = t & 31;
    *(float4*)&Vts[r * 132 + 4 * c4] = *(const float4*)&Vm[(size_t)r * DD + 4 * c4];
  }
  const float* Wm = W + ((size_t)m * SEQ + s0) * RR;
  for (int t = tid; t < 512; t += 256) {  // 32 rows x 16 float4
    int s = t >> 4, c4 = t & 15;
    *(float4*)&Ws[s * 68 + 4 * c4] = *(const float4*)&Wm[(size_t)s * RR + 4 * c4];
  }
  __syncthreads();
  const int ti = tid >> 5;  // 0..7 -> rows 4ti..+3
  const int tj = tid & 31;  // cols 4tj..+3
  float acc[4][4] = {{0.f,0.f,0.f,0.f},{0.f,0.f,0.f,0.f},
                     {0.f,0.f,0.f,0.f},{0.f,0.f,0.f,0.f}};
#pragma unroll 4
  for (int k = 0; k < RR; ++k) {
    float4 bv = *(float4*)&Vts[k * 132 + 4 * tj];
    float a0 = Ws[(4 * ti + 0) * 68 + k];
    float a1 = Ws[(4 * ti + 1) * 68 + k];
    float a2 = Ws[(4 * ti + 2) * 68 + k];
    float a3 = Ws[(4 * ti + 3) * 68 + k];
    acc[0][0] += a0 * bv.x; acc[0][1] += a0 * bv.y;
    acc[0][2] += a0 * bv.z; acc[0][3] += a0 * bv.w;
    acc[1][0] += a1 * bv.x; acc[1][1] += a1 * bv.y;
    acc[1][2] += a1 * bv.z; acc[1][3] += a1 * bv.w;
    acc[2][0] += a2 * bv.x; acc[2][1] += a2 * bv.y;
    acc[2][2] += a2 * bv.z; acc[2][3] += a2 * bv.w;
    acc[3][0] += a3 * bv.x; acc[3][1] += a3 * bv.y;
    acc[3][2] += a3 * bv.z; acc[3][3] += a3 * bv.w;
  }
  float* Om = out + ((size_t)m * SEQ + s0) * DD;
#pragma unroll
  for (int d = 0; d < 4; ++d) {
    float4 v = make_float4(acc[d][0], acc[d][1], acc[d][2], acc[d][3]);
    *(float4*)&Om[(size_t)(4 * ti + d) * DD + 4 * tj] = v;
  }
}

extern "C" void kernel_launch(void* const* d_in, const int* in_sizes, int n_in,
                              void* d_out, int out_size, void* d_ws, size_t ws_size,
                              hipStream_t stream) {
  (void)in_sizes; (void)n_in; (void)out_size; (void)ws_size;
  const float* X = (const float*)d_in[0];  // rank (d_in[1]) is fixed at 64
  float* out = (float*)d_out;
  char* ws = (char*)d_ws;
  float* G = (float*)ws;
  float* Vfull = (float*)(ws + OFF_VFULL);
  float* normg = (float*)(ws + OFF_NORM);
  float* Vt = (float*)(ws + OFF_VT);
  float* W = (float*)ws;  // overlays dead G/Vfull/normg

  gram_k<<<dim3(4, NM), 256, 0, stream>>>(X, G);
  jacobi1s_k<<<NM, 1024, 0, stream>>>(G, Vfull, normg);
  select_k<<<NM, 128, 0, stream>>>(Vfull, normg, Vt);
  gemm1_k<<<dim3(SEQ / 32, NM), 256, 0, stream>>>(X, Vt, W);
  gemm2_k<<<dim3(SEQ / 32, NM), 256, 0, stream>>>(W, Vt, out);
}